// Round 5
// baseline (1805.238 us; speedup 1.0000x reference)
//
#include <hip/hip_runtime.h>

#define NN 100000   // nodes
#define NE 1600000  // edges
#define CC 128      // channels
#define GG 50       // gaussians
#define EPB 128     // edges per block
#define KSH 18      // sub-bin shift: k = e >> 18, 7 bins < 8
#define NSORT (NN * 8)          // 800000 scan entries
#define NSCB2 782               // ceil(800000/1024)

typedef _Float16 half8 __attribute__((ext_vector_type(8)));
typedef float f32x4 __attribute__((ext_vector_type(4)));

static __device__ __forceinline__ f32x4 mfma16(half8 a, half8 b, f32x4 c) {
    return __builtin_amdgcn_mfma_f32_16x16x32_f16(a, b, c, 0, 0, 0);
}

// ---------------------------------------------------------------------------
// Pack fn1 / fn2 weights into MFMA B-fragment order (f16) in ws.
// b1frag: [nb=8][ks=2][lane=64][8] at 0 (16 KB); b2frag: [nb=8][ks=4][lane=64][8] at +8192 (32 KB)
// ---------------------------------------------------------------------------
__global__ __launch_bounds__(256) void pack_frags(const float* fn1_w, const float* fn2_w,
                                                  _Float16* ws_frag)
{
    int tid = threadIdx.x;
    for (int s = tid; s < 1024; s += 256) {
        int l = s & 63, ks = (s >> 6) & 1, nb = s >> 7;
        int f = nb * 16 + (l & 15);
        int k0 = ks * 32 + 8 * (l >> 4);
        half8 v;
        #pragma unroll
        for (int i = 0; i < 8; i++) {
            int g = k0 + i;
            v[i] = (g < GG) ? (_Float16)fn1_w[f * GG + g] : (_Float16)0.f;
        }
        *reinterpret_cast<half8*>(&ws_frag[s * 8]) = v;
    }
    for (int s = tid; s < 2048; s += 256) {
        int l = s & 63, ks = (s >> 6) & 3, nb = s >> 8;
        int f = nb * 16 + (l & 15);
        int k0 = ks * 32 + 8 * (l >> 4);
        const float* wp = fn2_w + f * CC + k0;
        half8 v;
        #pragma unroll
        for (int i = 0; i < 8; i++) v[i] = (_Float16)wp[i];
        *reinterpret_cast<half8*>(&ws_frag[8192 + s * 8]) = v;
    }
}

// ---------------------------------------------------------------------------
// out[r][f] = sum_k in[r][k]*w[f][k] + bias[f]  (f16 MFMA, f32 accum)
// ---------------------------------------------------------------------------
template <typename OutT>
__global__ __launch_bounds__(256) void lin_kernel(const float* in, const float* w,
                                                  const float* bias, OutT* out, int nrows)
{
    __shared__ __align__(16) _Float16 a_lds[64][136];
    __shared__ __align__(16) _Float16 bfrag[2048 * 8];

    int tid = threadIdx.x;
    int rowBase = blockIdx.x * 64;

    for (int i = tid; i < 64 * 32; i += 256) {
        int r = i >> 5, c4 = i & 31;
        float4 v = {0.f, 0.f, 0.f, 0.f};
        if (rowBase + r < nrows)
            v = reinterpret_cast<const float4*>(in)[(size_t)(rowBase + r) * (CC / 4) + c4];
        a_lds[r][c4 * 4 + 0] = (_Float16)v.x;
        a_lds[r][c4 * 4 + 1] = (_Float16)v.y;
        a_lds[r][c4 * 4 + 2] = (_Float16)v.z;
        a_lds[r][c4 * 4 + 3] = (_Float16)v.w;
    }
    for (int s = tid; s < 2048; s += 256) {
        int l = s & 63, ks = (s >> 6) & 3, nb = s >> 8;
        int f = nb * 16 + (l & 15);
        int k0 = ks * 32 + 8 * (l >> 4);
        const float* wp = w + f * CC + k0;
        half8 v;
        #pragma unroll
        for (int i = 0; i < 8; i++) v[i] = (_Float16)wp[i];
        *reinterpret_cast<half8*>(&bfrag[s * 8]) = v;
    }
    __syncthreads();

    int wid = tid >> 6, l = tid & 63;
    int lr = l & 15, lg = l >> 4;
    int wrow = wid * 16;

    half8 afr[4];
    #pragma unroll
    for (int ks = 0; ks < 4; ks++)
        afr[ks] = *reinterpret_cast<const half8*>(&a_lds[wrow + lr][ks * 32 + 8 * lg]);

    #pragma unroll
    for (int nb = 0; nb < 8; nb++) {
        f32x4 acc = {0.f, 0.f, 0.f, 0.f};
        #pragma unroll
        for (int ks = 0; ks < 4; ks++) {
            half8 bf = *reinterpret_cast<const half8*>(&bfrag[((nb * 4 + ks) * 64 + l) * 8]);
            acc = mfma16(afr[ks], bf, acc);
        }
        float bv = bias[nb * 16 + lr];
        #pragma unroll
        for (int j = 0; j < 4; j++) {
            int r = rowBase + wrow + lg * 4 + j;
            if (r < nrows) out[(size_t)r * CC + nb * 16 + lr] = (OutT)(acc[j] + bv);
        }
    }
}

// ------------------- counting sort by (row, edge-range) ---------------------
__global__ __launch_bounds__(256) void hist_kernel(const int* row, int* cnt) {
    int e = blockIdx.x * 256 + threadIdx.x;
    if (e < NE) {
        int r = row[e];
        int k = e >> KSH;
        atomicAdd(&cnt[r * 8 + k], 1);
    }
}

__global__ __launch_bounds__(256) void scanA(const int* cnt, int* excl, int* bsum, int n) {
    __shared__ int lds[256];
    int b = blockIdx.x, t = threadIdx.x;
    int base = b * 1024 + t * 4;
    int v[4];
    #pragma unroll
    for (int i = 0; i < 4; i++) v[i] = (base + i < n) ? cnt[base + i] : 0;
    int s = v[0] + v[1] + v[2] + v[3];
    lds[t] = s;
    __syncthreads();
    for (int off = 1; off < 256; off <<= 1) {
        int x = (t >= off) ? lds[t - off] : 0;
        __syncthreads();
        lds[t] += x;
        __syncthreads();
    }
    int incl = lds[t];
    int run = incl - s;
    #pragma unroll
    for (int i = 0; i < 4; i++) {
        if (base + i < n) excl[base + i] = run;
        run += v[i];
    }
    if (t == 255) bsum[b] = incl;
}

__global__ __launch_bounds__(256) void scanB(int* bsum, int n) {
    __shared__ int lds[256];
    int t = threadIdx.x;
    int base = t * 4;
    int v[4];
    #pragma unroll
    for (int i = 0; i < 4; i++) v[i] = (base + i < n) ? bsum[base + i] : 0;
    int s = v[0] + v[1] + v[2] + v[3];
    lds[t] = s;
    __syncthreads();
    for (int off = 1; off < 256; off <<= 1) {
        int x = (t >= off) ? lds[t - off] : 0;
        __syncthreads();
        lds[t] += x;
        __syncthreads();
    }
    int run = lds[t] - s;
    #pragma unroll
    for (int i = 0; i < 4; i++) {
        if (base + i < n) bsum[base + i] = run;
        run += v[i];
    }
}

// adds block offsets; extracts pristine row starts: rowptr2[r] = excl[r*8]
__global__ __launch_bounds__(256) void scanC(int* excl, const int* bsum, int* rowptr2, int n) {
    int b = blockIdx.x, t = threadIdx.x;
    int off = bsum[b];
    int base = b * 1024 + t * 4;
    #pragma unroll
    for (int i = 0; i < 4; i++) {
        int idx = base + i;
        if (idx < n) {
            int val = excl[idx] + off;
            excl[idx] = val;
            if ((idx & 7) == 0) rowptr2[idx >> 3] = val;
        }
    }
}

__global__ __launch_bounds__(256) void build_perm(const int* row, int* cursor, int* perm) {
    int e = blockIdx.x * 256 + threadIdx.x;
    if (e < NE) {
        int r = row[e];
        int k = e >> KSH;
        int p = atomicAdd(&cursor[r * 8 + k], 1);
        perm[p] = e;
    }
}

// ---------------------------------------------------------------------------
// Shared tile pipeline: ea (swizzled, rows [0,nAct)) -> h -> msg, all in u_lds.
// Barriers at block scope; inactive waves skip compute only.
// ---------------------------------------------------------------------------
__device__ __forceinline__ void tile_compute(
    unsigned char* u_lds, const int* col_l,
    const _Float16* __restrict__ frag_ws,
    const float* __restrict__ fn1_b, const float* __restrict__ fn2_b,
    const _Float16* __restrict__ x1, int tid, int nAct)
{
    int l = tid & 63, w = tid >> 6;
    int lr = l & 15, lg = l >> 4;
    int erow = w * 16;
    bool act = erow < nAct;

    half8 a1[2];
    if (act) {
        #pragma unroll
        for (int ks = 0; ks < 2; ks++) {
            int e = erow + lr;
            int byte = e * 128 + ((ks * 64 + lg * 16) ^ ((e & 7) << 4));
            a1[ks] = *reinterpret_cast<const half8*>(u_lds + byte);
        }
    }
    __syncthreads();   // ea reads done before h overwrite

    if (act) {
        #pragma unroll
        for (int nb = 0; nb < 8; nb++) {
            half8 b10 = *reinterpret_cast<const half8*>(&frag_ws[((nb * 2 + 0) * 64 + l) * 8]);
            half8 b11 = *reinterpret_cast<const half8*>(&frag_ws[((nb * 2 + 1) * 64 + l) * 8]);
            f32x4 acc = {0.f, 0.f, 0.f, 0.f};
            acc = mfma16(a1[0], b10, acc);
            acc = mfma16(a1[1], b11, acc);
            float bv = fn1_b[nb * 16 + lr];
            int f = nb * 16 + lr;
            #pragma unroll
            for (int j = 0; j < 4; j++) {
                float z = acc[j] + bv;
                float t = __expf(-fabsf(z));
                float h = fmaxf(z, 0.f) + __logf(1.f + t) - 0.69314718055994531f;
                int e = erow + lg * 4 + j;
                int byte = e * 256 + ((f * 2) ^ ((e & 7) << 4));
                *reinterpret_cast<_Float16*>(u_lds + byte) = (_Float16)h;
            }
        }
    }
    __syncthreads();   // h ready

    if (act) {
        half8 a2[4];
        #pragma unroll
        for (int ks = 0; ks < 4; ks++) {
            int e = erow + lr;
            int byte = e * 256 + ((ks * 64 + lg * 16) ^ ((e & 7) << 4));
            a2[ks] = *reinterpret_cast<const half8*>(u_lds + byte);
        }
        int cc4[4];
        #pragma unroll
        for (int j = 0; j < 4; j++) cc4[j] = col_l[erow + lg * 4 + j];

        const half8* b2g = reinterpret_cast<const half8*>(frag_ws + 8192);
        #pragma unroll
        for (int nb = 0; nb < 8; nb++) {
            f32x4 acc = {0.f, 0.f, 0.f, 0.f};
            #pragma unroll
            for (int ks = 0; ks < 4; ks++) {
                half8 bf = b2g[(nb * 4 + ks) * 64 + l];
                acc = mfma16(a2[ks], bf, acc);
            }
            float bv = fn2_b[nb * 16 + lr];
            int f = nb * 16 + lr;
            #pragma unroll
            for (int j = 0; j < 4; j++) {
                int e = erow + lg * 4 + j;
                float wv = acc[j] + bv;
                float xv = (float)x1[(size_t)cc4[j] * CC + f];
                int byte = e * 256 + ((f * 2) ^ ((e & 7) << 4));
                *reinterpret_cast<_Float16*>(u_lds + byte) = (_Float16)(xv * wv);
            }
        }
    }
}

// gather ea rows [0,nAct) from perm[src0..] into u_lds (swizzled); also col_l
__device__ __forceinline__ void gather_tile(
    unsigned char* u_lds, int* col_l, const int* __restrict__ perm,
    const int* __restrict__ eidx, const float* __restrict__ ea,
    int tid, int src0, int nAct)
{
    int i = tid >> 2, p = tid & 3;
    if (i < nAct) {
        int pe = perm[src0 + i];
        if (p == 0) col_l[i] = eidx[(size_t)NE + pe];
        const float2* src = reinterpret_cast<const float2*>(ea + (size_t)pe * GG);
        int swz = (i & 7) << 4;
        #pragma unroll
        for (int it = 0; it < 7; it++) {
            int g2 = p + it * 4;
            if (g2 < 25) {
                float2 v = src[g2];
                int byte = i * 128 + ((g2 * 4) ^ swz);
                _Float16* q = reinterpret_cast<_Float16*>(u_lds + byte);
                q[0] = (_Float16)v.x;
                q[1] = (_Float16)v.y;
            }
        }
        #pragma unroll
        for (int it = 0; it < 2; it++) {
            int g2 = 25 + p + it * 4;
            if (g2 < 32) {
                int byte = i * 128 + ((g2 * 4) ^ swz);
                _Float16* q = reinterpret_cast<_Float16*>(u_lds + byte);
                q[0] = (_Float16)0.f;
                q[1] = (_Float16)0.f;
            }
        }
    }
}

// ---------------------------------------------------------------------------
// Owner-block edge kernel: zero atomics.
// Block b owns every row whose sorted segment STARTS in [b*128,(b+1)*128).
// Interior rows -> plain store; last row -> accumulator + spill tiles.
// ---------------------------------------------------------------------------
__global__ __launch_bounds__(512, 8) void edge_kernel_owner(
    const _Float16* __restrict__ x1, const int* __restrict__ eidx,
    const float* __restrict__ ea, const _Float16* __restrict__ frag_ws,
    const float* __restrict__ fn1_b, const float* __restrict__ fn2_b,
    const int* __restrict__ perm, const int* __restrict__ rowptr2,
    float* __restrict__ agg)
{
    __shared__ __align__(16) unsigned char u_lds[EPB * CC * 2];  // 32 KB
    __shared__ int pe_l[EPB];
    __shared__ int row_l[EPB];
    __shared__ int col_l[EPB];

    int tid = threadIdx.x;
    int base = blockIdx.x * EPB;

    if (tid < EPB) pe_l[tid] = perm[base + tid];
    __syncthreads();
    if (tid < EPB) {
        int pe = pe_l[tid];
        row_l[tid] = eidx[pe];
        col_l[tid] = eidx[(size_t)NE + pe];
    }
    // gather ea for main tile (uses pe_l, synced above)
    {
        int i = tid >> 2, p = tid & 3;
        int pe = pe_l[i];
        const float2* src = reinterpret_cast<const float2*>(ea + (size_t)pe * GG);
        int swz = (i & 7) << 4;
        #pragma unroll
        for (int it = 0; it < 7; it++) {
            int g2 = p + it * 4;
            if (g2 < 25) {
                float2 v = src[g2];
                int byte = i * 128 + ((g2 * 4) ^ swz);
                _Float16* q = reinterpret_cast<_Float16*>(u_lds + byte);
                q[0] = (_Float16)v.x;
                q[1] = (_Float16)v.y;
            }
        }
        #pragma unroll
        for (int it = 0; it < 2; it++) {
            int g2 = 25 + p + it * 4;
            if (g2 < 32) {
                int byte = i * 128 + ((g2 * 4) ^ swz);
                _Float16* q = reinterpret_cast<_Float16*>(u_lds + byte);
                q[0] = (_Float16)0.f;
                q[1] = (_Float16)0.f;
            }
        }
    }
    __syncthreads();

    int r0 = row_l[0];
    int rl = row_l[EPB - 1];
    bool owned0 = (rowptr2[r0] == base);
    bool ownedL = (rowptr2[rl] >= base);
    int endLast = (rl + 1 < NN) ? rowptr2[rl + 1] : NE;

    // main tile: ea -> h -> msg (in u_lds)
    tile_compute(u_lds, col_l, frag_ws, fn1_b, fn2_b, x1, tid, EPB);
    __syncthreads();   // msg ready

    // serial segmented reduce over the 128 sorted edges; plain stores only
    float lastAcc = 0.f;
    if (tid < 128) {
        int f = tid;
        float acc = 0.f;
        int cur = row_l[0];
        bool firstRun = true;
        for (int i = 0; i < EPB; i++) {
            int r = row_l[i];
            if (r != cur) {   // uniform across the 2 reduce waves
                if (!firstRun || owned0) agg[(size_t)cur * CC + f] = acc;
                firstRun = false;
                acc = 0.f;
                cur = r;
            }
            int byte = i * 256 + ((f * 2) ^ ((i & 7) << 4));
            acc += (float)*reinterpret_cast<const _Float16*>(u_lds + byte);
        }
        lastAcc = acc;   // cur == rl here
    }

    // spill tiles: remaining edges of rl (all rows == rl), only if we own it
    for (int t0 = base + EPB; ownedL && t0 < endLast; t0 += EPB) {
        int S = endLast - t0;
        if (S > EPB) S = EPB;
        __syncthreads();   // protect u_lds until reduce done
        gather_tile(u_lds, col_l, perm, eidx, ea, tid, t0, S);
        __syncthreads();
        tile_compute(u_lds, col_l, frag_ws, fn1_b, fn2_b, x1, tid, S);
        __syncthreads();
        if (tid < 128) {
            int f = tid;
            for (int k = 0; k < S; k++) {
                int byte = k * 256 + ((f * 2) ^ ((k & 7) << 4));
                lastAcc += (float)*reinterpret_cast<const _Float16*>(u_lds + byte);
            }
        }
    }
    if (ownedL && tid < 128) agg[(size_t)rl * CC + tid] = lastAcc;
}

// ---------------- fallback atomic edge kernel (no sort needed) --------------
__global__ __launch_bounds__(512, 8) void edge_kernel_atomic(
    const _Float16* __restrict__ x1, const int* __restrict__ eidx,
    const float* __restrict__ ea, const _Float16* __restrict__ frag_ws,
    const float* __restrict__ fn1_b, const float* __restrict__ fn2_b,
    float* __restrict__ agg)
{
    __shared__ __align__(16) unsigned char u_lds[EPB * CC * 2];
    __shared__ int rows_l[EPB];
    __shared__ int cols_l[EPB];

    int tid = threadIdx.x;
    size_t eBase = (size_t)blockIdx.x * EPB;

    if (tid < EPB) {
        rows_l[tid] = eidx[eBase + tid];
        cols_l[tid] = eidx[(size_t)NE + eBase + tid];
    }
    {
        const float2* eap = reinterpret_cast<const float2*>(ea + eBase * GG);
        for (int i = tid; i < EPB * 25; i += 512) {
            int e = i / 25, g2 = i - e * 25;
            float2 v = eap[i];
            int byte = e * 128 + ((g2 * 4) ^ ((e & 7) << 4));
            _Float16* p = reinterpret_cast<_Float16*>(u_lds + byte);
            p[0] = (_Float16)v.x;
            p[1] = (_Float16)v.y;
        }
        for (int i = tid; i < EPB * 14; i += 512) {
            int e = i / 14, g = (i - e * 14) + 50;
            int byte = e * 128 + ((g * 2) ^ ((e & 7) << 4));
            *reinterpret_cast<_Float16*>(u_lds + byte) = (_Float16)0.f;
        }
    }
    __syncthreads();

    tile_compute(u_lds, cols_l, frag_ws, fn1_b, fn2_b, x1, tid, EPB);
    __syncthreads();

    int w = tid >> 6, l = tid & 63;
    int lr = l & 15, lg = l >> 4;
    int erow = w * 16;
    #pragma unroll
    for (int nb = 0; nb < 8; nb++) {
        int f = nb * 16 + lr;
        #pragma unroll
        for (int j = 0; j < 4; j++) {
            int e = erow + lg * 4 + j;
            int byte = e * 256 + ((f * 2) ^ ((e & 7) << 4));
            float mv = (float)*reinterpret_cast<const _Float16*>(u_lds + byte);
            atomicAdd(&agg[(size_t)rows_l[e] * CC + f], mv);
        }
    }
}

extern "C" void kernel_launch(void* const* d_in, const int* in_sizes, int n_in,
                              void* d_out, int out_size, void* d_ws, size_t ws_size,
                              hipStream_t stream) {
    const float* x      = (const float*)d_in[0];
    const int*   eidx   = (const int*)d_in[1];
    const float* ea     = (const float*)d_in[2];
    const float* lin1_w = (const float*)d_in[3];
    const float* lin1_b = (const float*)d_in[4];
    const float* lin2_w = (const float*)d_in[5];
    const float* lin2_b = (const float*)d_in[6];
    const float* fn1_w  = (const float*)d_in[7];
    const float* fn1_b  = (const float*)d_in[8];
    const float* fn2_w  = (const float*)d_in[9];
    const float* fn2_b  = (const float*)d_in[10];

    float* out = (float*)d_out;
    float* agg = out;

    // ws layout (bytes)
    const size_t o_frag = 0;                                   // 48 KB used
    const size_t o_x1h  = 65536;                               // 25.6 MB
    const size_t o_perm = o_x1h + (size_t)NN * CC * 2;         // 6.4 MB
    const size_t o_cur  = o_perm + (size_t)NE * 4;             // 3.2 MB (hist->scan->cursor)
    const size_t o_rp2  = o_cur + (size_t)NSORT * 4;           // 400 KB
    const size_t o_bsum = o_rp2 + (size_t)NN * 4;              // 4 KB
    const size_t req    = o_bsum + 4096;

    _Float16* frag_ws = (_Float16*)((char*)d_ws + o_frag);
    _Float16* x1h     = (_Float16*)((char*)d_ws + o_x1h);

    hipMemsetAsync(agg, 0, (size_t)NN * CC * sizeof(float), stream);
    pack_frags<<<1, 256, 0, stream>>>(fn1_w, fn2_w, frag_ws);
    lin_kernel<_Float16><<<(NN + 63) / 64, 256, 0, stream>>>(x, lin1_w, lin1_b, x1h, NN);

    if (ws_size >= req) {
        int* perm    = (int*)((char*)d_ws + o_perm);
        int* cursor  = (int*)((char*)d_ws + o_cur);
        int* rowptr2 = (int*)((char*)d_ws + o_rp2);
        int* bsum    = (int*)((char*)d_ws + o_bsum);

        hipMemsetAsync(cursor, 0, (size_t)NSORT * 4, stream);
        hist_kernel<<<(NE + 255) / 256, 256, 0, stream>>>(eidx, cursor);
        scanA<<<NSCB2, 256, 0, stream>>>(cursor, cursor, bsum, NSORT);
        scanB<<<1, 256, 0, stream>>>(bsum, NSCB2);
        scanC<<<NSCB2, 256, 0, stream>>>(cursor, bsum, rowptr2, NSORT);
        build_perm<<<(NE + 255) / 256, 256, 0, stream>>>(eidx, cursor, perm);

        edge_kernel_owner<<<NE / EPB, 512, 0, stream>>>(x1h, eidx, ea, frag_ws,
                                                        fn1_b, fn2_b, perm, rowptr2, agg);
    } else {
        edge_kernel_atomic<<<NE / EPB, 512, 0, stream>>>(x1h, eidx, ea, frag_ws,
                                                         fn1_b, fn2_b, agg);
    }

    lin_kernel<float><<<(NN + 63) / 64, 256, 0, stream>>>(agg, lin2_w, lin2_b, out, NN);
}

// Round 6
// 854.172 us; speedup vs baseline: 2.1134x; 2.1134x over previous
//
#include <hip/hip_runtime.h>

#define NN 100000   // nodes
#define NE 1600000  // edges
#define CC 128      // channels
#define GG 50       // gaussians
#define EPB 128     // edges per block

typedef _Float16 half8 __attribute__((ext_vector_type(8)));
typedef _Float16 half2v __attribute__((ext_vector_type(2)));
typedef float f32x4 __attribute__((ext_vector_type(4)));

static __device__ __forceinline__ f32x4 mfma16(half8 a, half8 b, f32x4 c) {
    return __builtin_amdgcn_mfma_f32_16x16x32_f16(a, b, c, 0, 0, 0);
}

// packed f16x2 atomic add, fire-and-forget (no return, no CAS loop)
static __device__ __forceinline__ void atomic_pk_add_f16(_Float16* addr, unsigned pk) {
    asm volatile("global_atomic_pk_add_f16 %0, %1, off"
                 :: "v"(addr), "v"(pk) : "memory");
}

// ---------------------------------------------------------------------------
// Pack fn1 / fn2 weights into MFMA B-fragment order (f16) in ws.
// b1frag: [nb=8][ks=2][lane=64][8] at 0 (16 KB); b2frag: [nb=8][ks=4][lane=64][8] at +8192 (32 KB)
// lane l holds B[k0..k0+7][f], f = nb*16+(l&15), k0 = ks*32 + 8*(l>>4)
// ---------------------------------------------------------------------------
__global__ __launch_bounds__(256) void pack_frags(const float* fn1_w, const float* fn2_w,
                                                  _Float16* ws_frag)
{
    int tid = threadIdx.x;
    for (int s = tid; s < 1024; s += 256) {
        int l = s & 63, ks = (s >> 6) & 1, nb = s >> 7;
        int f = nb * 16 + (l & 15);
        int k0 = ks * 32 + 8 * (l >> 4);
        half8 v;
        #pragma unroll
        for (int i = 0; i < 8; i++) {
            int g = k0 + i;
            v[i] = (g < GG) ? (_Float16)fn1_w[f * GG + g] : (_Float16)0.f;
        }
        *reinterpret_cast<half8*>(&ws_frag[s * 8]) = v;
    }
    for (int s = tid; s < 2048; s += 256) {
        int l = s & 63, ks = (s >> 6) & 3, nb = s >> 8;
        int f = nb * 16 + (l & 15);
        int k0 = ks * 32 + 8 * (l >> 4);
        const float* wp = fn2_w + f * CC + k0;
        half8 v;
        #pragma unroll
        for (int i = 0; i < 8; i++) v[i] = (_Float16)wp[i];
        *reinterpret_cast<half8*>(&ws_frag[8192 + s * 8]) = v;
    }
}

// ---------------------------------------------------------------------------
// out[r][f] = sum_k in[r][k]*w[f][k] + bias[f]  (f16 MFMA, f32 accum)
// 64 rows/block, 256 threads. InT/OutT = float or _Float16.
// ---------------------------------------------------------------------------
template <typename InT, typename OutT>
__global__ __launch_bounds__(256) void lin_kernel(const InT* in, const float* w,
                                                  const float* bias, OutT* out, int nrows)
{
    __shared__ __align__(16) _Float16 a_lds[64][136];
    __shared__ __align__(16) _Float16 bfrag[2048 * 8];

    int tid = threadIdx.x;
    int rowBase = blockIdx.x * 64;

    if constexpr (sizeof(InT) == 4) {
        for (int i = tid; i < 64 * 32; i += 256) {
            int r = i >> 5, c4 = i & 31;
            float4 v = {0.f, 0.f, 0.f, 0.f};
            if (rowBase + r < nrows)
                v = reinterpret_cast<const float4*>(in)[(size_t)(rowBase + r) * (CC / 4) + c4];
            a_lds[r][c4 * 4 + 0] = (_Float16)v.x;
            a_lds[r][c4 * 4 + 1] = (_Float16)v.y;
            a_lds[r][c4 * 4 + 2] = (_Float16)v.z;
            a_lds[r][c4 * 4 + 3] = (_Float16)v.w;
        }
    } else {
        for (int i = tid; i < 64 * 16; i += 256) {
            int r = i >> 4, c8 = i & 15;
            half8 v;
            #pragma unroll
            for (int k = 0; k < 8; k++) v[k] = (_Float16)0.f;
            if (rowBase + r < nrows)
                v = reinterpret_cast<const half8*>(in)[(size_t)(rowBase + r) * (CC / 8) + c8];
            *reinterpret_cast<half8*>(&a_lds[r][c8 * 8]) = v;
        }
    }
    for (int s = tid; s < 2048; s += 256) {
        int l = s & 63, ks = (s >> 6) & 3, nb = s >> 8;
        int f = nb * 16 + (l & 15);
        int k0 = ks * 32 + 8 * (l >> 4);
        const float* wp = w + f * CC + k0;
        half8 v;
        #pragma unroll
        for (int i = 0; i < 8; i++) v[i] = (_Float16)wp[i];
        *reinterpret_cast<half8*>(&bfrag[s * 8]) = v;
    }
    __syncthreads();

    int wid = tid >> 6, l = tid & 63;
    int lr = l & 15, lg = l >> 4;
    int wrow = wid * 16;

    half8 afr[4];
    #pragma unroll
    for (int ks = 0; ks < 4; ks++)
        afr[ks] = *reinterpret_cast<const half8*>(&a_lds[wrow + lr][ks * 32 + 8 * lg]);

    #pragma unroll
    for (int nb = 0; nb < 8; nb++) {
        f32x4 acc = {0.f, 0.f, 0.f, 0.f};
        #pragma unroll
        for (int ks = 0; ks < 4; ks++) {
            half8 bf = *reinterpret_cast<const half8*>(&bfrag[((nb * 4 + ks) * 64 + l) * 8]);
            acc = mfma16(afr[ks], bf, acc);
        }
        float bv = bias[nb * 16 + lr];
        #pragma unroll
        for (int j = 0; j < 4; j++) {
            int r = rowBase + wrow + lg * 4 + j;
            if (r < nrows) out[(size_t)r * CC + nb * 16 + lr] = (OutT)(acc[j] + bv);
        }
    }
}

// ---------------------------------------------------------------------------
// Fused edge kernel: 128 edges/block, 512 threads (8 waves x 16 edges).
// LDS: union{ea[128][64]f16 | h[128][128]f16} = 32K + idx 1K -> 4 blocks/CU.
// Scatter via packed f16x2 atomics (halves transaction count vs f32);
// x1 gathered as f16x2 pairs on even lanes (halves gather transactions).
// ---------------------------------------------------------------------------
__global__ __launch_bounds__(512, 8) void edge_kernel_pk(
    const _Float16* __restrict__ x1, const int* __restrict__ eidx,
    const float* __restrict__ ea, const _Float16* __restrict__ frag_ws,
    const float* __restrict__ fn1_b, const float* __restrict__ fn2_b,
    _Float16* __restrict__ aggH)
{
    __shared__ __align__(16) unsigned char u_lds[EPB * CC * 2];  // 32 KB
    __shared__ int rows_l[EPB];
    __shared__ int cols_l[EPB];

    int tid = threadIdx.x;
    size_t eBase = (size_t)blockIdx.x * EPB;

    if (tid < EPB) {
        rows_l[tid] = eidx[eBase + tid];
        cols_l[tid] = eidx[(size_t)NE + eBase + tid];
    }
    // edge_attr tile -> f16 LDS, swizzled rows of 64 (g 50..63 zero-padded)
    {
        const float2* eap = reinterpret_cast<const float2*>(ea + eBase * GG);
        for (int i = tid; i < EPB * 25; i += 512) {
            int e = i / 25, g2 = i - e * 25;
            float2 v = eap[i];
            int byte = e * 128 + ((g2 * 4) ^ ((e & 7) << 4));
            _Float16* p = reinterpret_cast<_Float16*>(u_lds + byte);
            p[0] = (_Float16)v.x;
            p[1] = (_Float16)v.y;
        }
        for (int i = tid; i < EPB * 14; i += 512) {
            int e = i / 14, g = (i - e * 14) + 50;
            int byte = e * 128 + ((g * 2) ^ ((e & 7) << 4));
            *reinterpret_cast<_Float16*>(u_lds + byte) = (_Float16)0.f;
        }
    }
    __syncthreads();

    int w = tid >> 6, l = tid & 63;
    int lr = l & 15, lg = l >> 4;
    int erow = w * 16;

    // stage-1 A fragments (each wave owns its 16 edges)
    half8 a1[2];
    #pragma unroll
    for (int ks = 0; ks < 2; ks++) {
        int e = erow + lr;
        int byte = e * 128 + ((ks * 64 + lg * 16) ^ ((e & 7) << 4));
        a1[ks] = *reinterpret_cast<const half8*>(u_lds + byte);
    }
    __syncthreads();  // all ea reads complete before h overwrites u_lds

    // ---- stage 1: h = shifted_softplus(ea @ fn1^T + b1) -> u_lds [128][256B]
    #pragma unroll
    for (int nb = 0; nb < 8; nb++) {
        half8 b10 = *reinterpret_cast<const half8*>(&frag_ws[((nb * 2 + 0) * 64 + l) * 8]);
        half8 b11 = *reinterpret_cast<const half8*>(&frag_ws[((nb * 2 + 1) * 64 + l) * 8]);
        f32x4 acc = {0.f, 0.f, 0.f, 0.f};
        acc = mfma16(a1[0], b10, acc);
        acc = mfma16(a1[1], b11, acc);
        float bv = fn1_b[nb * 16 + lr];
        int f = nb * 16 + lr;
        #pragma unroll
        for (int j = 0; j < 4; j++) {
            float z = acc[j] + bv;
            float t = __expf(-fabsf(z));
            float h = fmaxf(z, 0.f) + __logf(1.f + t) - 0.69314718055994531f;
            int e = erow + lg * 4 + j;
            int byte = e * 256 + ((f * 2) ^ ((e & 7) << 4));
            *reinterpret_cast<_Float16*>(u_lds + byte) = (_Float16)h;
        }
    }
    __syncthreads();

    // ---- stage 2: W = h @ fn2^T + b2 ; scatter x1[col]*W via pk f16 atomics
    half8 a2[4];
    #pragma unroll
    for (int ks = 0; ks < 4; ks++) {
        int e = erow + lr;
        int byte = e * 256 + ((ks * 64 + lg * 16) ^ ((e & 7) << 4));
        a2[ks] = *reinterpret_cast<const half8*>(u_lds + byte);
    }

    int rr[4], cc4[4];
    #pragma unroll
    for (int j = 0; j < 4; j++) {
        int e = erow + lg * 4 + j;
        rr[j] = rows_l[e];
        cc4[j] = cols_l[e];
    }

    const half8* b2g = reinterpret_cast<const half8*>(frag_ws + 8192);
    #pragma unroll
    for (int nb = 0; nb < 8; nb++) {
        f32x4 acc = {0.f, 0.f, 0.f, 0.f};
        #pragma unroll
        for (int ks = 0; ks < 4; ks++) {
            half8 bf = b2g[(nb * 4 + ks) * 64 + l];
            acc = mfma16(a2[ks], bf, acc);
        }
        float bv = fn2_b[nb * 16 + lr];
        int f = nb * 16 + lr;
        #pragma unroll
        for (int j = 0; j < 4; j++) {
            float wv = acc[j] + bv;          // channel f of edge e(j)
            float wv2 = __shfl_xor(wv, 1);   // channel f+1 (from odd lane)
            if (!(l & 1)) {
                unsigned xp = *reinterpret_cast<const unsigned*>(
                    &x1[(size_t)cc4[j] * CC + f]);       // f16 pair (f, f+1)
                half2v xv = __builtin_bit_cast(half2v, xp);
                half2v h;
                h[0] = (_Float16)((float)xv[0] * wv);
                h[1] = (_Float16)((float)xv[1] * wv2);
                atomic_pk_add_f16(&aggH[(size_t)rr[j] * CC + f],
                                  __builtin_bit_cast(unsigned, h));
            }
        }
    }
}

extern "C" void kernel_launch(void* const* d_in, const int* in_sizes, int n_in,
                              void* d_out, int out_size, void* d_ws, size_t ws_size,
                              hipStream_t stream) {
    const float* x      = (const float*)d_in[0];
    const int*   eidx   = (const int*)d_in[1];
    const float* ea     = (const float*)d_in[2];
    const float* lin1_w = (const float*)d_in[3];
    const float* lin1_b = (const float*)d_in[4];
    const float* lin2_w = (const float*)d_in[5];
    const float* lin2_b = (const float*)d_in[6];
    const float* fn1_w  = (const float*)d_in[7];
    const float* fn1_b  = (const float*)d_in[8];
    const float* fn2_w  = (const float*)d_in[9];
    const float* fn2_b  = (const float*)d_in[10];

    float* out = (float*)d_out;

    // ws layout: frags 64KB | x1h 25.6MB | aggH 25.6MB  (total 51.27 MB)
    _Float16* frag_ws = (_Float16*)d_ws;
    _Float16* x1h     = (_Float16*)((char*)d_ws + 65536);
    _Float16* aggH    = (_Float16*)((char*)d_ws + 65536 + (size_t)NN * CC * 2);

    hipMemsetAsync(aggH, 0, (size_t)NN * CC * 2, stream);
    pack_frags<<<1, 256, 0, stream>>>(fn1_w, fn2_w, frag_ws);
    lin_kernel<float, _Float16><<<(NN + 63) / 64, 256, 0, stream>>>(x, lin1_w, lin1_b, x1h, NN);
    edge_kernel_pk<<<NE / EPB, 512, 0, stream>>>(x1h, eidx, ea, frag_ws, fn1_b, fn2_b, aggH);
    lin_kernel<_Float16, float><<<(NN + 63) / 64, 256, 0, stream>>>(aggH, lin2_w, lin2_b, out, NN);
}